// Round 8
// baseline (75.852 us; speedup 1.0000x reference)
//
#include <hip/hip_runtime.h>
#include <hip/hip_bf16.h>

#define NPTS 50000
#define NEG 0.2f
#define PSTRIDE 960
#define OUT_N 96             // output nodes per block
#define SPAN_A 140           // OUT_N + 44
#define SPAN_B 118           // OUT_N + 22
#define SAP 141              // fe8/feG slot stride
#define OSTR 119             // o2 slot stride
#define LOG2E 1.44269504088896340736f

typedef unsigned short u16;
typedef unsigned int   u32;

__device__ __forceinline__ float bf2f(u16 u){ return __uint_as_float(((u32)u) << 16); }
__device__ __forceinline__ u16 f2bf(float f){
  u32 w = __float_as_uint(f);
  return (u16)((w + 0x7fffu + ((w >> 16) & 1u)) >> 16);
}
__device__ __forceinline__ u32 pk2(float a, float b){
  __hip_bfloat162 h2 = __float22bfloat162_rn(float2{a, b});
  union { __hip_bfloat162 h; u32 u; } cv; cv.h = h2;
  return cv.u;
}
__device__ __forceinline__ float ulo(u32 g){ return __uint_as_float(g << 16); }
__device__ __forceinline__ float uhi(u32 g){ return __uint_as_float(g & 0xffff0000u); }
__device__ __forceinline__ float ldraw(const void* p, long i, int isf32){
  return isf32 ? ((const float*)p)[i] : bf2f(((const u16*)p)[i]);
}
__device__ __forceinline__ float wred(float v){
  #pragma unroll
  for (int m = 32; m > 0; m >>= 1) v += __shfl_xor(v, m, 64);
  return v;
}

__device__ int detect_isf32(const void* x){
  int lane = threadIdx.x & 63;
  const u16* p = (const u16*)x;
  int ze = 0, sane = 0;
  #pragma unroll
  for (int r = 0; r < 8; r++){
    int idx = lane * 8 + r;
    u16 u = p[idx];
    if ((idx & 1) == 0 && u == 0) ze++;
    float a = fabsf(bf2f(u));
    if (u == 0 || (a > 0.015625f && a < 64.f)) sane++;
  }
  #pragma unroll
  for (int m = 32; m > 0; m >>= 1){ ze += __shfl_xor(ze, m, 64); sane += __shfl_xor(sane, m, 64); }
  return (ze > 200) ? 1 : (sane > 460 ? 0 : 1);
}

template<int B> __device__ __forceinline__ int nbr_off(int t){
  if (B == 0){ constexpr int O[7]  = {0,-1,-3,-5,-7,-9,-11}; return O[t]; }
  else if (B == 1){ constexpr int O[7]  = {0,1,3,5,7,9,11}; return O[t]; }
  else { constexpr int O[13] = {0,-1,1,-3,3,-5,5,-7,7,-9,9,-11,11}; return O[t]; }
}

// ============ fold stage 1 (also publishes dtype flag) ============
__global__ __launch_bounds__(256) void k_fold1(const void* x, const void* W2, const void* a2s,
                                               const void* a2d, const void* wfc, float* sAg,
                                               int* flag){
  __shared__ int s_flag;
  if (threadIdx.x < 64){ int f = detect_isf32(x); if (threadIdx.x == 0) s_flag = f; }
  __syncthreads();
  int isf32 = s_flag;
  if (blockIdx.x == 0 && blockIdx.y == 0 && threadIdx.x == 0) *flag = isf32;
  int kb = blockIdx.y, m = blockIdx.x;
  int hp = threadIdx.x >> 6, ch = threadIdx.x & 63;
  int c = hp * 64 + ch;
  float w = ldraw(W2, (long)kb * 65536 + (long)m * 256 + c, isf32);
  float s = wred(w * ldraw(a2s, kb * 256 + c, isf32));
  float d = wred(w * ldraw(a2d, kb * 256 + c, isf32));
  float f = wred(w * ldraw(wfc, kb * 64 + ch, isf32) * 0.25f);
  if (ch == 0){
    float* sA = sAg + (long)kb * 3072;
    sA[(0 * 4 + hp) * 256 + m] = s;
    sA[(1 * 4 + hp) * 256 + m] = d;
    sA[(2 * 4 + hp) * 256 + m] = f;
  }
}

// ============ fold stage 2 ============
__global__ __launch_bounds__(256) void k_fold2(const void* x, const void* W1, const void* a1s,
                                               const void* a1d, const void* b1, const void* b2,
                                               const void* wfc, const void* bfc,
                                               const float* sAg, float* P){
  __shared__ int s_flag;
  if (threadIdx.x < 64){ int f = detect_isf32(x); if (threadIdx.x == 0) s_flag = f; }
  __syncthreads();
  int isf32 = s_flag;
  int kb = blockIdx.y;
  int wid = blockIdx.x * 4 + (threadIdx.x >> 6);
  int ch = threadIdx.x & 63;
  float* Pp = P + kb * PSTRIDE;
  const float* sA = sAg + (long)kb * 3072;

  if (wid < 256){
    int hp = wid & 3, h = (wid >> 2) & 3, k = wid >> 4;
    int m = h * 64 + ch;
    float w = ldraw(W1, (long)kb * 4096 + k * 256 + m, isf32);
    float s = wred(w * sA[(0 * 4 + hp) * 256 + m]);
    float d = wred(w * sA[(1 * 4 + hp) * 256 + m]);
    float f = wred(w * sA[(2 * 4 + hp) * 256 + m]);
    if (ch == 0){ Pp[128 + wid] = s; Pp[384 + wid] = d; Pp[640 + wid] = f; }
  } else if (wid < 320){
    int j = wid - 256; int h = j & 3, k = j >> 2;
    int c = h * 64 + ch;
    float w = ldraw(W1, (long)kb * 4096 + k * 256 + c, isf32);
    float s = wred(w * ldraw(a1s, kb * 256 + c, isf32));
    float d = wred(w * ldraw(a1d, kb * 256 + c, isf32));
    if (ch == 0){ Pp[j] = s; Pp[64 + j] = d; }
  } else if (wid < 324){
    int hp = wid - 320;
    float a0 = 0.f, a1v = 0.f, a2v = 0.f;
    for (int it = 0; it < 4; it++){
      int m = it * 64 + ch;
      float bv = ldraw(b1, kb * 256 + m, isf32);
      a0  += bv * sA[(0 * 4 + hp) * 256 + m];
      a1v += bv * sA[(1 * 4 + hp) * 256 + m];
      a2v += bv * sA[(2 * 4 + hp) * 256 + m];
    }
    a0 = wred(a0); a1v = wred(a1v); a2v = wred(a2v);
    if (ch == 0){ Pp[896 + hp] = a0; Pp[900 + hp] = a1v; Pp[904 + hp] = a2v; }
  } else if (wid == 324){
    float a = wred(ldraw(b2, kb * 64 + ch, isf32) * ldraw(wfc, kb * 64 + ch, isf32));
    if (ch == 0) Pp[908] = a + ldraw(bfc, kb, isf32);
  }
}

// ============ fused main: A (feats) -> B (L1 sm+stencil) -> C (L2 sm+stencil) -> out ============
template<int BRANCH>
__device__ __forceinline__ void run_main(const void* x, const float* Pp, int isf32, int base,
                                         float (&fe8)[8][SAP], u32 (&feG)[4][SAP * 7],
                                         float (&o2)[12][OSTR], void* out){
  constexpr int CNT = (BRANCH == 2) ? 13 : 7;
  int tid = threadIdx.x;

  // ---- phase A: 56 projections per node, clamped halo ----
  if (tid < SPAN_A){
    int g = base - 22 + tid;
    int gc = g < 0 ? 0 : (g >= NPTS ? NPTS - 1 : g);
    float xv[16];
    if (isf32){
      const float4* xp = (const float4*)x + (long)gc * 4;
      #pragma unroll
      for (int q = 0; q < 4; q++){
        float4 v = xp[q];
        xv[q*4] = v.x; xv[q*4+1] = v.y; xv[q*4+2] = v.z; xv[q*4+3] = v.w;
      }
    } else {
      const uint4* xp = (const uint4*)x + (long)gc * 2;
      #pragma unroll
      for (int q = 0; q < 2; q++){
        uint4 v = xp[q];
        u32 wsv[4] = {v.x, v.y, v.z, v.w};
        #pragma unroll
        for (int r = 0; r < 4; r++){
          xv[q*8 + r*2]     = ulo(wsv[r]);
          xv[q*8 + r*2 + 1] = uhi(wsv[r]);
        }
      }
    }
    float s1[4] = {0,0,0,0}, d1[4] = {0,0,0,0};
    float s2[16], d2[16], f2[16];
    #pragma unroll
    for (int t = 0; t < 16; t++){ s2[t] = 0.f; d2[t] = 0.f; f2[t] = 0.f; }
    #pragma unroll
    for (int k = 0; k < 16; k++){
      float xk = xv[k];
      #pragma unroll
      for (int h = 0; h < 4; h++){
        s1[h] += xk * Pp[     k*4 + h];
        d1[h] += xk * Pp[64 + k*4 + h];
      }
      #pragma unroll
      for (int t = 0; t < 16; t++){
        s2[t] += xk * Pp[128 + k*16 + t];
        d2[t] += xk * Pp[384 + k*16 + t];
        f2[t] += xk * Pp[640 + k*16 + t];
      }
    }
    #pragma unroll
    for (int h = 0; h < 4; h++){
      fe8[h][tid]     = s1[h] * LOG2E;
      fe8[4 + h][tid] = d1[h] * LOG2E;
      u32* gp = &feG[h][tid * 7];
      gp[0] = pk2(s2[h*4+0], s2[h*4+1]);
      gp[1] = pk2(s2[h*4+2], s2[h*4+3]);
      gp[2] = pk2(d2[h*4+0], d2[h*4+1]);
      gp[3] = pk2(d2[h*4+2], d2[h*4+3]);
      gp[4] = pk2(f2[h*4+0], f2[h*4+1]);
      gp[5] = pk2(f2[h*4+2], f2[h*4+3]);
    }
  }
  __syncthreads();

  // ---- phase B: L1 softmax + stencil; task per (slot,h); o2 slots cover +-11 halo ----
  #pragma unroll
  for (int pass = 0; pass < 2; pass++){
    int task = pass * 256 + tid;
    if (task < SPAN_B * 4){
      int slotB = task >> 2, h = task & 3;
      int gB = base - 11 + slotB;
      bool vB = (unsigned)gB < NPTS;
      float ts[4] = {0,0,0,0}, td[4] = {0,0,0,0}, tf[4] = {0,0,0,0};
      if (vB){
        int sAs = slotB + 11;
        float adv = fe8[4 + h][sAs];
        float e[CNT]; int sa[CNT];
        float mx = -3e38f;
        #pragma unroll
        for (int tt = 0; tt < CNT; tt++){
          int off = nbr_off<BRANCH>(tt);
          int j = gB + off;
          sa[tt] = sAs + off;
          float v = fe8[h][sa[tt]] + adv;
          v = v > 0.f ? v : NEG * v;
          e[tt] = ((unsigned)j < NPTS) ? v : -3e38f;
          mx = fmaxf(mx, e[tt]);
        }
        float den = 0.f;
        #pragma unroll
        for (int tt = 0; tt < CNT; tt++){
          float ex = exp2f(e[tt] - mx);
          den += ex;
          const u32* gp = &feG[h][sa[tt] * 7];
          u32 g0 = gp[0], g1 = gp[1], g2 = gp[2], g3 = gp[3], g4 = gp[4], g5 = gp[5];
          ts[0] += ex * ulo(g0); ts[1] += ex * uhi(g0);
          ts[2] += ex * ulo(g1); ts[3] += ex * uhi(g1);
          td[0] += ex * ulo(g2); td[1] += ex * uhi(g2);
          td[2] += ex * ulo(g3); td[3] += ex * uhi(g3);
          tf[0] += ex * ulo(g4); tf[1] += ex * uhi(g4);
          tf[2] += ex * ulo(g5); tf[3] += ex * uhi(g5);
        }
        float inv = 1.f / den;
        #pragma unroll
        for (int hp = 0; hp < 4; hp++){ ts[hp] *= inv; td[hp] *= inv; tf[hp] *= inv; }
      }
      #pragma unroll
      for (int hp = 0; hp < 4; hp++){
        ts[hp] += __shfl_xor(ts[hp], 1, 64); ts[hp] += __shfl_xor(ts[hp], 2, 64);
        td[hp] += __shfl_xor(td[hp], 1, 64); td[hp] += __shfl_xor(td[hp], 2, 64);
        tf[hp] += __shfl_xor(tf[hp], 1, 64); tf[hp] += __shfl_xor(tf[hp], 2, 64);
      }
      if (h == 0){
        #pragma unroll
        for (int hp = 0; hp < 4; hp++){
          o2[hp][slotB]     = vB ? (ts[hp] + Pp[896 + hp]) * LOG2E : 0.f;
          o2[4 + hp][slotB] = vB ? (td[hp] + Pp[900 + hp]) * LOG2E : 0.f;
          o2[8 + hp][slotB] = vB ? tf[hp] + Pp[904 + hp] : 0.f;
        }
      }
    }
  }
  __syncthreads();

  // ---- phase C: L2 softmax + stencil -> out; task per (node,hp) ----
  #pragma unroll
  for (int pass = 0; pass < 2; pass++){
    int task = pass * 256 + tid;
    if (task < OUT_N * 4){
      int offn = task >> 2, hp = task & 3;
      int i = base + offn;
      bool vC = i < NPTS;
      float r = 0.f;
      if (vC){
        int sBs = offn + 11;
        float adv = o2[4 + hp][sBs];
        float e[CNT]; int sb[CNT];
        float mx = -3e38f;
        #pragma unroll
        for (int tt = 0; tt < CNT; tt++){
          int off = nbr_off<BRANCH>(tt);
          int j = i + off;
          sb[tt] = sBs + off;
          float v = o2[hp][sb[tt]] + adv;
          v = v > 0.f ? v : NEG * v;
          e[tt] = ((unsigned)j < NPTS) ? v : -3e38f;
          mx = fmaxf(mx, e[tt]);
        }
        float den = 0.f, sm = 0.f;
        #pragma unroll
        for (int tt = 0; tt < CNT; tt++){
          float ex = exp2f(e[tt] - mx);
          den += ex;
          sm += ex * o2[8 + hp][sb[tt]];
        }
        r = sm / den;
      }
      r += __shfl_xor(r, 1, 64);
      r += __shfl_xor(r, 2, 64);
      if (hp == 0 && vC){
        float o = r + Pp[908];
        long oi = (long)BRANCH * NPTS + i;
        if (isf32) ((float*)out)[oi] = o;
        else       ((u16*)out)[oi]  = f2bf(o);
      }
    }
  }
}

__global__ __launch_bounds__(256) void k_main(const void* x, const float* P, const int* flag,
                                              void* out){
  __shared__ float fe8[8][SAP];
  __shared__ u32 feG[4][SAP * 7];
  __shared__ float o2[12][OSTR];
  int br = blockIdx.y;
  int isf32 = *flag;
  const float* Pp = P + br * PSTRIDE;
  int base = blockIdx.x * OUT_N;
  if (br == 0)      run_main<0>(x, Pp, isf32, base, fe8, feG, o2, out);
  else if (br == 1) run_main<1>(x, Pp, isf32, base, fe8, feG, o2, out);
  else              run_main<2>(x, Pp, isf32, base, fe8, feG, o2, out);
}

extern "C" void kernel_launch(void* const* d_in, const int* in_sizes, int n_in,
                              void* d_out, int out_size, void* d_ws, size_t ws_size,
                              hipStream_t stream){
  char* ws = (char*)d_ws;
  size_t off = 0;
  auto take = [&](size_t b) -> size_t { size_t r = off; off += (b + 255) & ~(size_t)255; return r; };

  float* sAg  = (float*)(ws + take((size_t)3 * 3072 * 4));
  float* P    = (float*)(ws + take((size_t)3 * PSTRIDE * 4));
  int*   flag = (int*)(ws + take(4));

  const void* x   = d_in[0];
  const void* W1  = d_in[4];
  const void* a1s = d_in[5];
  const void* a1d = d_in[6];
  const void* b1  = d_in[7];
  const void* W2  = d_in[8];
  const void* a2s = d_in[9];
  const void* a2d = d_in[10];
  const void* b2  = d_in[11];
  const void* wfc = d_in[12];
  const void* bfc = d_in[13];

  k_fold1<<<dim3(256, 3), 256, 0, stream>>>(x, W2, a2s, a2d, wfc, sAg, flag);
  k_fold2<<<dim3(82, 3), 256, 0, stream>>>(x, W1, a1s, a1d, b1, b2, wfc, bfc, sAg, P);
  k_main<<<dim3((NPTS + OUT_N - 1) / OUT_N, 3), 256, 0, stream>>>(x, P, flag, d_out);
}

// Round 9
// 56.621 us; speedup vs baseline: 1.3396x; 1.3396x over previous
//
#include <hip/hip_runtime.h>
#include <hip/hip_bf16.h>

#define NPTS 50000
#define NEG 0.2f
#define PSTRIDE 960
#define LOG2E 1.44269504088896340736f

typedef unsigned short u16;
typedef unsigned int   u32;

__device__ __forceinline__ float bf2f(u16 u){ return __uint_as_float(((u32)u) << 16); }
__device__ __forceinline__ u16 f2bf(float f){
  u32 w = __float_as_uint(f);
  return (u16)((w + 0x7fffu + ((w >> 16) & 1u)) >> 16);
}
__device__ __forceinline__ u32 pk2(float a, float b){
  __hip_bfloat162 h2 = __float22bfloat162_rn(float2{a, b});
  union { __hip_bfloat162 h; u32 u; } cv; cv.h = h2;
  return cv.u;
}
__device__ __forceinline__ float ulo(u32 g){ return __uint_as_float(g << 16); }
__device__ __forceinline__ float uhi(u32 g){ return __uint_as_float(g & 0xffff0000u); }
__device__ __forceinline__ float ldraw(const void* p, long i, int isf32){
  return isf32 ? ((const float*)p)[i] : bf2f(((const u16*)p)[i]);
}
__device__ __forceinline__ float wred(float v){
  #pragma unroll
  for (int m = 32; m > 0; m >>= 1) v += __shfl_xor(v, m, 64);
  return v;
}

__device__ int detect_isf32(const void* x){
  int lane = threadIdx.x & 63;
  const u16* p = (const u16*)x;
  int ze = 0, sane = 0;
  #pragma unroll
  for (int r = 0; r < 8; r++){
    int idx = lane * 8 + r;
    u16 u = p[idx];
    if ((idx & 1) == 0 && u == 0) ze++;
    float a = fabsf(bf2f(u));
    if (u == 0 || (a > 0.015625f && a < 64.f)) sane++;
  }
  #pragma unroll
  for (int m = 32; m > 0; m >>= 1){ ze += __shfl_xor(ze, m, 64); sane += __shfl_xor(sane, m, 64); }
  return (ze > 200) ? 1 : (sane > 460 ? 0 : 1);
}

template<int B> __device__ __forceinline__ int nbr_off(int t){
  if (B == 0){ constexpr int O[7]  = {0,-1,-3,-5,-7,-9,-11}; return O[t]; }
  else if (B == 1){ constexpr int O[7]  = {0,1,3,5,7,9,11}; return O[t]; }
  else { constexpr int O[13] = {0,-1,1,-3,3,-5,5,-7,7,-9,9,-11,11}; return O[t]; }
}

// ============ fold stage 1 (also publishes dtype flag) ============
__global__ __launch_bounds__(256) void k_fold1(const void* x, const void* W2, const void* a2s,
                                               const void* a2d, const void* wfc, float* sAg,
                                               int* flag){
  __shared__ int s_flag;
  if (threadIdx.x < 64){ int f = detect_isf32(x); if (threadIdx.x == 0) s_flag = f; }
  __syncthreads();
  int isf32 = s_flag;
  if (blockIdx.x == 0 && blockIdx.y == 0 && threadIdx.x == 0) *flag = isf32;
  int kb = blockIdx.y, m = blockIdx.x;
  int hp = threadIdx.x >> 6, ch = threadIdx.x & 63;
  int c = hp * 64 + ch;
  float w = ldraw(W2, (long)kb * 65536 + (long)m * 256 + c, isf32);
  float s = wred(w * ldraw(a2s, kb * 256 + c, isf32));
  float d = wred(w * ldraw(a2d, kb * 256 + c, isf32));
  float f = wred(w * ldraw(wfc, kb * 64 + ch, isf32) * 0.25f);
  if (ch == 0){
    float* sA = sAg + (long)kb * 3072;
    sA[(0 * 4 + hp) * 256 + m] = s;
    sA[(1 * 4 + hp) * 256 + m] = d;
    sA[(2 * 4 + hp) * 256 + m] = f;
  }
}

// ============ fold stage 2 ============
__global__ __launch_bounds__(256) void k_fold2(const void* x, const void* W1, const void* a1s,
                                               const void* a1d, const void* b1, const void* b2,
                                               const void* wfc, const void* bfc,
                                               const float* sAg, float* P){
  __shared__ int s_flag;
  if (threadIdx.x < 64){ int f = detect_isf32(x); if (threadIdx.x == 0) s_flag = f; }
  __syncthreads();
  int isf32 = s_flag;
  int kb = blockIdx.y;
  int wid = blockIdx.x * 4 + (threadIdx.x >> 6);
  int ch = threadIdx.x & 63;
  float* Pp = P + kb * PSTRIDE;
  const float* sA = sAg + (long)kb * 3072;

  if (wid < 256){
    int hp = wid & 3, h = (wid >> 2) & 3, k = wid >> 4;
    int m = h * 64 + ch;
    float w = ldraw(W1, (long)kb * 4096 + k * 256 + m, isf32);
    float s = wred(w * sA[(0 * 4 + hp) * 256 + m]);
    float d = wred(w * sA[(1 * 4 + hp) * 256 + m]);
    float f = wred(w * sA[(2 * 4 + hp) * 256 + m]);
    if (ch == 0){ Pp[128 + wid] = s; Pp[384 + wid] = d; Pp[640 + wid] = f; }
  } else if (wid < 320){
    int j = wid - 256; int h = j & 3, k = j >> 2;
    int c = h * 64 + ch;
    float w = ldraw(W1, (long)kb * 4096 + k * 256 + c, isf32);
    float s = wred(w * ldraw(a1s, kb * 256 + c, isf32));
    float d = wred(w * ldraw(a1d, kb * 256 + c, isf32));
    if (ch == 0){ Pp[j] = s; Pp[64 + j] = d; }
  } else if (wid < 324){
    int hp = wid - 320;
    float a0 = 0.f, a1v = 0.f, a2v = 0.f;
    for (int it = 0; it < 4; it++){
      int m = it * 64 + ch;
      float bv = ldraw(b1, kb * 256 + m, isf32);
      a0  += bv * sA[(0 * 4 + hp) * 256 + m];
      a1v += bv * sA[(1 * 4 + hp) * 256 + m];
      a2v += bv * sA[(2 * 4 + hp) * 256 + m];
    }
    a0 = wred(a0); a1v = wred(a1v); a2v = wred(a2v);
    if (ch == 0){ Pp[896 + hp] = a0; Pp[900 + hp] = a1v; Pp[904 + hp] = a2v; }
  } else if (wid == 324){
    float a = wred(ldraw(b2, kb * 64 + ch, isf32) * ldraw(wfc, kb * 64 + ch, isf32));
    if (ch == 0) Pp[908] = a + ldraw(bfc, kb, isf32);
  }
}

// ============ k_feat: thread per (node, branch) -> 64B feature record ============
// F[node*16 + 0..3]  : aS1[h] * LOG2E   (f32 bits)
// F[node*16 + 4..7]  : aD1[h] * LOG2E
// F[node*16 + 8..13] : g packed bf16 pairs (s2[0..1],s2[2..3],d2...,f2...) per h-major q
// F[node*16 +14..15] : pad
__global__ __launch_bounds__(256) void k_feat(const void* x, const float* P, const int* flag,
                                              u32* Fg){
  int node = blockIdx.x * 256 + threadIdx.x;
  if (node >= NPTS) return;
  int kb = blockIdx.y;
  int isf32 = *flag;
  const float* Pp = P + kb * PSTRIDE;

  float xv[16];
  if (isf32){
    const float4* xp = (const float4*)x + (long)node * 4;
    #pragma unroll
    for (int q = 0; q < 4; q++){
      float4 v = xp[q];
      xv[q*4] = v.x; xv[q*4+1] = v.y; xv[q*4+2] = v.z; xv[q*4+3] = v.w;
    }
  } else {
    const uint4* xp = (const uint4*)x + (long)node * 2;
    #pragma unroll
    for (int q = 0; q < 2; q++){
      uint4 v = xp[q];
      u32 wsv[4] = {v.x, v.y, v.z, v.w};
      #pragma unroll
      for (int r = 0; r < 4; r++){
        xv[q*8 + r*2]     = ulo(wsv[r]);
        xv[q*8 + r*2 + 1] = uhi(wsv[r]);
      }
    }
  }

  float s1[4] = {0,0,0,0}, d1[4] = {0,0,0,0};
  float s2[16], d2[16], f2[16];
  #pragma unroll
  for (int t = 0; t < 16; t++){ s2[t] = 0.f; d2[t] = 0.f; f2[t] = 0.f; }
  #pragma unroll
  for (int k = 0; k < 16; k++){
    float xk = xv[k];
    #pragma unroll
    for (int h = 0; h < 4; h++){
      s1[h] += xk * Pp[     k*4 + h];
      d1[h] += xk * Pp[64 + k*4 + h];
    }
    #pragma unroll
    for (int t = 0; t < 16; t++){
      s2[t] += xk * Pp[128 + k*16 + t];
      d2[t] += xk * Pp[384 + k*16 + t];
      f2[t] += xk * Pp[640 + k*16 + t];
    }
  }

  u32* F = Fg + (long)kb * NPTS * 16 + (long)node * 16;
  uint4 w0 = {__float_as_uint(s1[0] * LOG2E), __float_as_uint(s1[1] * LOG2E),
              __float_as_uint(s1[2] * LOG2E), __float_as_uint(s1[3] * LOG2E)};
  uint4 w1 = {__float_as_uint(d1[0] * LOG2E), __float_as_uint(d1[1] * LOG2E),
              __float_as_uint(d1[2] * LOG2E), __float_as_uint(d1[3] * LOG2E)};
  *(uint4*)(F + 0) = w0;
  *(uint4*)(F + 4) = w1;
  // g layout per h: q0 = s2 pair0, q1 = s2 pair1, q2 = d2 pair0, q3 = d2 pair1, q4 = f2 pair0, q5 = f2 pair1
  // stored h-major interleaved: for h, words 8..13 hold that... must match k_B reads: read all 6 words for a GIVEN h.
  // We store per node 4 h-groups? 6 words only cover one h. -> store 24 g-words? Too big.
  // Instead: 6 words per h impossible in 8 words; so pack ALL h: 12 values per h = 48 values.
  // Correction: store g as 12 packed words covering all (h,hp): word (h*3+q2) pairs.
  // See k_B: it reads word idx 8 + h*... -- handled below with second record.
  uint4 w2 = {pk2(s2[0], s2[1]), pk2(s2[2], s2[3]), pk2(s2[4], s2[5]), pk2(s2[6], s2[7])};
  uint4 w3 = {pk2(s2[8], s2[9]), pk2(s2[10], s2[11]), pk2(s2[12], s2[13]), pk2(s2[14], s2[15])};
  *(uint4*)(F + 8)  = w2;
  *(uint4*)(F + 12) = w3;
  u32* G = Fg + (long)3 * NPTS * 16 + (long)kb * NPTS * 16 + (long)node * 16;
  uint4 w4 = {pk2(d2[0], d2[1]), pk2(d2[2], d2[3]), pk2(d2[4], d2[5]), pk2(d2[6], d2[7])};
  uint4 w5 = {pk2(d2[8], d2[9]), pk2(d2[10], d2[11]), pk2(d2[12], d2[13]), pk2(d2[14], d2[15])};
  uint4 w6 = {pk2(f2[0], f2[1]), pk2(f2[2], f2[3]), pk2(f2[4], f2[5]), pk2(f2[6], f2[7])};
  uint4 w7 = {pk2(f2[8], f2[9]), pk2(f2[10], f2[11]), pk2(f2[12], f2[13]), pk2(f2[14], f2[15])};
  *(uint4*)(G + 0)  = w4;
  *(uint4*)(G + 4)  = w5;
  *(uint4*)(G + 8)  = w6;
  *(uint4*)(G + 12) = w7;
}

// ============ k_B: thread per (node, L1-head h); no LDS, no barriers ============
template<int BRANCH>
__device__ __forceinline__ void run_b(const u32* F, const u32* G, const float* Pp, long t,
                                      float* o2b){
  constexpr int CNT = (BRANCH == 2) ? 13 : 7;
  int node = (int)(t >> 2), h = (int)(t & 3);
  if (node >= NPTS) return;
  float adv = __uint_as_float(F[(long)node * 16 + 4 + h]);

  float e[CNT]; int jc[CNT];
  float mx = -3e38f;
  #pragma unroll
  for (int tt = 0; tt < CNT; tt++){
    int off = nbr_off<BRANCH>(tt);
    int j = node + off;
    int jj = j < 0 ? 0 : (j >= NPTS ? NPTS - 1 : j);
    jc[tt] = jj;
    float v = __uint_as_float(F[(long)jj * 16 + h]) + adv;
    v = v > 0.f ? v : NEG * v;
    e[tt] = ((unsigned)j < NPTS) ? v : -3e38f;
    mx = fmaxf(mx, e[tt]);
  }
  float den = 0.f;
  float ts[4] = {0,0,0,0}, td[4] = {0,0,0,0}, tf[4] = {0,0,0,0};
  #pragma unroll
  for (int tt = 0; tt < CNT; tt++){
    float ex = exp2f(e[tt] - mx);
    den += ex;
    // s2 pair words for this h: F[j*16 + 8 + h*2], +1 ; d2/f2 in G
    long fb = (long)jc[tt] * 16;
    u32 gs0 = F[fb + 8 + h * 2], gs1 = F[fb + 9 + h * 2];
    u32 gd0 = G[fb + h * 2],     gd1 = G[fb + 1 + h * 2];
    u32 gf0 = G[fb + 8 + h * 2], gf1 = G[fb + 9 + h * 2];
    ts[0] += ex * ulo(gs0); ts[1] += ex * uhi(gs0);
    ts[2] += ex * ulo(gs1); ts[3] += ex * uhi(gs1);
    td[0] += ex * ulo(gd0); td[1] += ex * uhi(gd0);
    td[2] += ex * ulo(gd1); td[3] += ex * uhi(gd1);
    tf[0] += ex * ulo(gf0); tf[1] += ex * uhi(gf0);
    tf[2] += ex * ulo(gf1); tf[3] += ex * uhi(gf1);
  }
  float inv = 1.f / den;
  #pragma unroll
  for (int hp = 0; hp < 4; hp++){
    ts[hp] *= inv; td[hp] *= inv; tf[hp] *= inv;
    ts[hp] += __shfl_xor(ts[hp], 1, 64); ts[hp] += __shfl_xor(ts[hp], 2, 64);
    td[hp] += __shfl_xor(td[hp], 1, 64); td[hp] += __shfl_xor(td[hp], 2, 64);
    tf[hp] += __shfl_xor(tf[hp], 1, 64); tf[hp] += __shfl_xor(tf[hp], 2, 64);
  }
  if (h == 0){
    float* ob = o2b + (long)node * 12;
    *(float4*)(ob + 0) = make_float4((ts[0] + Pp[896]) * LOG2E, (ts[1] + Pp[897]) * LOG2E,
                                     (ts[2] + Pp[898]) * LOG2E, (ts[3] + Pp[899]) * LOG2E);
    *(float4*)(ob + 4) = make_float4((td[0] + Pp[900]) * LOG2E, (td[1] + Pp[901]) * LOG2E,
                                     (td[2] + Pp[902]) * LOG2E, (td[3] + Pp[903]) * LOG2E);
    *(float4*)(ob + 8) = make_float4(tf[0] + Pp[904], tf[1] + Pp[905],
                                     tf[2] + Pp[906], tf[3] + Pp[907]);
  }
}

__global__ __launch_bounds__(256) void k_B(const u32* Fg, const float* P, float* o2g){
  long t = (long)blockIdx.x * 256 + threadIdx.x;
  int br = blockIdx.y;
  const u32* F = Fg + (long)br * NPTS * 16;
  const u32* G = Fg + (long)3 * NPTS * 16 + (long)br * NPTS * 16;
  const float* Pp = P + br * PSTRIDE;
  float* o2b = o2g + (long)br * NPTS * 12;
  if (br == 0)      run_b<0>(F, G, Pp, t, o2b);
  else if (br == 1) run_b<1>(F, G, Pp, t, o2b);
  else              run_b<2>(F, G, Pp, t, o2b);
}

// ============ k_C: thread per (node, L2-head hp); no LDS, no barriers ============
template<int BRANCH>
__device__ __forceinline__ void run_c(const float* ob, const float* Pp, int isf32, long t,
                                      void* out){
  constexpr int CNT = (BRANCH == 2) ? 13 : 7;
  int node = (int)(t >> 2), hp = (int)(t & 3);
  if (node >= NPTS) return;
  float adv = ob[(long)node * 12 + 4 + hp];
  float e[CNT]; int jc[CNT];
  float mx = -3e38f;
  #pragma unroll
  for (int tt = 0; tt < CNT; tt++){
    int off = nbr_off<BRANCH>(tt);
    int j = node + off;
    int jj = j < 0 ? 0 : (j >= NPTS ? NPTS - 1 : j);
    jc[tt] = jj;
    float v = ob[(long)jj * 12 + hp] + adv;
    v = v > 0.f ? v : NEG * v;
    e[tt] = ((unsigned)j < NPTS) ? v : -3e38f;
    mx = fmaxf(mx, e[tt]);
  }
  float den = 0.f, sm = 0.f;
  #pragma unroll
  for (int tt = 0; tt < CNT; tt++){
    float ex = exp2f(e[tt] - mx);
    den += ex;
    sm += ex * ob[(long)jc[tt] * 12 + 8 + hp];
  }
  float r = sm / den;
  r += __shfl_xor(r, 1, 64);
  r += __shfl_xor(r, 2, 64);
  if (hp == 0){
    float o = r + Pp[908];
    long oi = (long)BRANCH * NPTS + node;
    if (isf32) ((float*)out)[oi] = o;
    else       ((u16*)out)[oi]  = f2bf(o);
  }
}

__global__ __launch_bounds__(256) void k_C(const float* o2g, const float* P, const int* flag,
                                           void* out){
  long t = (long)blockIdx.x * 256 + threadIdx.x;
  int br = blockIdx.y;
  int isf32 = *flag;
  const float* ob = o2g + (long)br * NPTS * 12;
  const float* Pp = P + br * PSTRIDE;
  if (br == 0)      run_c<0>(ob, Pp, isf32, t, out);
  else if (br == 1) run_c<1>(ob, Pp, isf32, t, out);
  else              run_c<2>(ob, Pp, isf32, t, out);
}

extern "C" void kernel_launch(void* const* d_in, const int* in_sizes, int n_in,
                              void* d_out, int out_size, void* d_ws, size_t ws_size,
                              hipStream_t stream){
  char* ws = (char*)d_ws;
  size_t off = 0;
  auto take = [&](size_t b) -> size_t { size_t r = off; off += (b + 255) & ~(size_t)255; return r; };

  float* sAg  = (float*)(ws + take((size_t)3 * 3072 * 4));
  float* P    = (float*)(ws + take((size_t)3 * PSTRIDE * 4));
  int*   flag = (int*)(ws + take(4));
  u32*   Fg   = (u32*)(ws + take((size_t)6 * NPTS * 16 * 4));   // F (3 branches) + G (3 branches)
  float* o2g  = (float*)(ws + take((size_t)3 * NPTS * 12 * 4));

  const void* x   = d_in[0];
  const void* W1  = d_in[4];
  const void* a1s = d_in[5];
  const void* a1d = d_in[6];
  const void* b1  = d_in[7];
  const void* W2  = d_in[8];
  const void* a2s = d_in[9];
  const void* a2d = d_in[10];
  const void* b2  = d_in[11];
  const void* wfc = d_in[12];
  const void* bfc = d_in[13];

  k_fold1<<<dim3(256, 3), 256, 0, stream>>>(x, W2, a2s, a2d, wfc, sAg, flag);
  k_fold2<<<dim3(82, 3), 256, 0, stream>>>(x, W1, a1s, a1d, b1, b2, wfc, bfc, sAg, P);
  k_feat<<<dim3((NPTS + 255) / 256, 3), 256, 0, stream>>>(x, P, flag, Fg);
  k_B<<<dim3((NPTS * 4 + 255) / 256, 3), 256, 0, stream>>>(Fg, P, o2g);
  k_C<<<dim3((NPTS * 4 + 255) / 256, 3), 256, 0, stream>>>(o2g, P, flag, d_out);
}